// Round 1
// baseline (411.577 us; speedup 1.0000x reference)
//
#include <hip/hip_runtime.h>

// Focal Tversky loss over (8,10,512,512) fp32 logits, (8,512,512) int32 targets.
// argmax(softmax(x)) == argmax(x) -> no softmax needed. Memory-bound:
// channels 1..9 (75.5 MB) + targets (8.4 MB) ~= 84 MB read once -> ~13.3 us floor.
//
// R2: ballot-based wave histogramming (no atomics in per-pixel path).
// R3 (this round): fuse hist + reduce into ONE kernel. Per-block counts are
// accumulated into 27 global counters with device-scope atomicAdd (27 atomics
// per block, ~2K adds/address spread over kernel lifetime), and the last block
// to finish (done-counter pattern) reads them back via coherent atomic loads
// and computes the loss. Eliminates the second dispatch + 221 KB partial
// round-trip. Rocprof showed the harness's 320 MiB re-poison fills (~2x51 us
// at 82% HBM peak) dominate the 132 us; this targets the ~29 us we control.

#define HW4     65536    // 512*512/4 (float4 groups per plane), = 2^16
#define NGROUPS 524288   // 8 * HW4
#define NBLK    2048     // NBLK*256 == NGROUPS (one float4 group per thread)

// workspace layout: acc[0..26] = counters (0..8 TP, 9..17 tgt, 18..26 pred),
// acc[27] = done-counter. All zeroed by hipMemsetAsync before launch.
__global__ __launch_bounds__(256) void ftl_fused(const float* __restrict__ inp,
                                                 const int* __restrict__ tgt,
                                                 unsigned int* __restrict__ acc,
                                                 float* __restrict__ out) {
    __shared__ unsigned int s[4][27];
    const int tid  = threadIdx.x;
    const int wave = tid >> 6;
    const int lane = tid & 63;

    const int i  = blockIdx.x * 256 + tid;     // 4-pixel group index
    const int b  = i >> 16;                    // image index
    const int gi = i & (HW4 - 1);              // group within image

    const float4* base = reinterpret_cast<const float4*>(inp)
                       + (((size_t)(b * 10 + 1)) << 16) + gi;  // channel 1

    float4 v = base[0];
    float bv0 = v.x, bv1 = v.y, bv2 = v.z, bv3 = v.w;
    int   bc0 = 1,   bc1 = 1,   bc2 = 1,   bc3 = 1;
#pragma unroll
    for (int c = 2; c <= 9; ++c) {
        float4 w = base[((size_t)(c - 1)) << 16];
        if (w.x > bv0) { bv0 = w.x; bc0 = c; }
        if (w.y > bv1) { bv1 = w.y; bc1 = c; }
        if (w.z > bv2) { bv2 = w.z; bc2 = c; }
        if (w.w > bv3) { bv3 = w.w; bc3 = c; }
    }

    const int4 t = reinterpret_cast<const int4*>(tgt)[i];

    unsigned int cTP[9], cT[9], cP[9];
#pragma unroll
    for (int j = 0; j < 9; ++j) { cTP[j] = 0u; cT[j] = 0u; cP[j] = 0u; }

    // per-component valid masks (t != 0), wave-uniform u64s
    const unsigned long long vx = __ballot(t.x != 0);
    const unsigned long long vy = __ballot(t.y != 0);
    const unsigned long long vz = __ballot(t.z != 0);
    const unsigned long long vw = __ballot(t.w != 0);

#pragma unroll
    for (int c = 1; c <= 9; ++c) {
        const int j = c - 1;
        {   // component x
            const unsigned long long tm = __ballot(t.x == c);
            const unsigned long long pm = __ballot(bc0 == c);
            cT[j]  += (unsigned int)__builtin_popcountll(tm);
            cP[j]  += (unsigned int)__builtin_popcountll(pm & vx);
            cTP[j] += (unsigned int)__builtin_popcountll(tm & pm);
        }
        {   // component y
            const unsigned long long tm = __ballot(t.y == c);
            const unsigned long long pm = __ballot(bc1 == c);
            cT[j]  += (unsigned int)__builtin_popcountll(tm);
            cP[j]  += (unsigned int)__builtin_popcountll(pm & vy);
            cTP[j] += (unsigned int)__builtin_popcountll(tm & pm);
        }
        {   // component z
            const unsigned long long tm = __ballot(t.z == c);
            const unsigned long long pm = __ballot(bc2 == c);
            cT[j]  += (unsigned int)__builtin_popcountll(tm);
            cP[j]  += (unsigned int)__builtin_popcountll(pm & vz);
            cTP[j] += (unsigned int)__builtin_popcountll(tm & pm);
        }
        {   // component w
            const unsigned long long tm = __ballot(t.w == c);
            const unsigned long long pm = __ballot(bc3 == c);
            cT[j]  += (unsigned int)__builtin_popcountll(tm);
            cP[j]  += (unsigned int)__builtin_popcountll(pm & vw);
            cTP[j] += (unsigned int)__builtin_popcountll(tm & pm);
        }
    }

    // combine 4 waves via plain LDS stores (counts are wave-uniform)
    if (lane == 0) {
#pragma unroll
        for (int j = 0; j < 9; ++j) {
            s[wave][j]      = cTP[j];
            s[wave][9 + j]  = cT[j];
            s[wave][18 + j] = cP[j];
        }
    }
    __syncthreads();

    // block total -> device-scope atomic accumulation (27 adds/block)
    if (tid < 27)
        atomicAdd(&acc[tid], s[0][tid] + s[1][tid] + s[2][tid] + s[3][tid]);

    // make this block's atomics globally visible, then count ourselves done
    __threadfence();
    __syncthreads();
    __shared__ unsigned int lastFlag;
    if (tid == 0)
        lastFlag = (atomicAdd(&acc[27], 1u) == NBLK - 1) ? 1u : 0u;
    __syncthreads();
    if (!lastFlag) return;

    // last block: coherent read-back of the 27 counters, then the epilogue
    __shared__ double cs[27];
    if (tid < 27)
        cs[tid] = (double)atomicAdd(&acc[tid], 0u);   // atomic load, device-coherent
    __syncthreads();
    if (tid == 0) {
        double loss = 0.0;
#pragma unroll
        for (int c = 0; c < 9; ++c) {
            const double TP = cs[c];
            const double FN = cs[9 + c]  - TP;
            const double FP = cs[18 + c] - TP;
            const double tv = (TP + 1.0) / (TP + 0.7 * FN + 0.3 * FP + 1.0);
            loss += pow(1.0 - tv, 4.0 / 3.0);
        }
        out[0] = (float)loss;
    }
}

extern "C" void kernel_launch(void* const* d_in, const int* in_sizes, int n_in,
                              void* d_out, int out_size, void* d_ws, size_t ws_size,
                              hipStream_t stream) {
    const float* inp = (const float*)d_in[0];
    const int*   tgt = (const int*)d_in[1];
    unsigned int* acc = (unsigned int*)d_ws;   // 27 counters + done-counter
    float* out = (float*)d_out;

    hipMemsetAsync(acc, 0, 32 * sizeof(unsigned int), stream);  // capturable memset node
    ftl_fused<<<dim3(NBLK), dim3(256), 0, stream>>>(inp, tgt, acc, out);
}

// Round 2
// 136.198 us; speedup vs baseline: 3.0219x; 3.0219x over previous
//
#include <hip/hip_runtime.h>

// Focal Tversky loss over (8,10,512,512) fp32 logits, (8,512,512) int32 targets.
// argmax(softmax(x)) == argmax(x) -> no softmax needed. Memory-bound:
// channels 1..9 (75.5 MB) + targets (8.4 MB) ~= 84 MB read once -> ~13.3 us floor
// (less when L3-resident: rocprof shows FETCH ~42 MB on graph replay).
//
// R2: ballot-based wave histogramming (no per-pixel atomics).     [132 us total]
// R3: fused hist+reduce, 2048 blocks x 28 atomics on ONE line ->  [412 us: FAIL]
//     same-line coherent-point serialization, ~5.7 ns/op * 57K = 325 us kernel.
// R4 (this round): keep fusion, kill the contention:
//     - 64 replica accumulators, one 128B line each (blockIdx&63) -> 64x less
//       same-line traffic, overlapped with other blocks' memory phase.
//     - 1024-thread blocks (512 blocks, exactly 2/CU) -> 512 done-atomics only.
//     - NO __threadfence anywhere: atomic->atomic ordering via __syncthreads'
//       vmcnt(0) drain; readback uses atomicAdd(p,0) coherent loads (the
//       pattern that already validated absmax=0 in R3).

#define HW4   65536     // 512*512/4 float4 groups per plane
#define BLKT  1024
#define NBLK  512       // NBLK*BLKT == 8*HW4 (one float4 group per thread)
#define NREP  64        // replica accumulators, one cache line each

// workspace: ws[r*32 + c] (r<64, c<27) replicas; ws[2048] = done counter.
// memsetAsync zeroes ws[0..2048].
__global__ __launch_bounds__(1024) void ftl_fused(const float* __restrict__ inp,
                                                  const int* __restrict__ tgt,
                                                  unsigned int* __restrict__ ws,
                                                  float* __restrict__ out) {
    __shared__ unsigned int s[16][27];
    const int tid  = threadIdx.x;
    const int wave = tid >> 6;
    const int lane = tid & 63;

    const int i  = blockIdx.x * BLKT + tid;    // 4-pixel group index
    const int b  = i >> 16;                    // image index
    const int gi = i & (HW4 - 1);              // group within image

    const float4* base = reinterpret_cast<const float4*>(inp)
                       + (((size_t)(b * 10 + 1)) << 16) + gi;  // channel 1

    float4 v = base[0];
    float bv0 = v.x, bv1 = v.y, bv2 = v.z, bv3 = v.w;
    int   bc0 = 1,   bc1 = 1,   bc2 = 1,   bc3 = 1;
#pragma unroll
    for (int c = 2; c <= 9; ++c) {
        float4 w = base[((size_t)(c - 1)) << 16];
        if (w.x > bv0) { bv0 = w.x; bc0 = c; }
        if (w.y > bv1) { bv1 = w.y; bc1 = c; }
        if (w.z > bv2) { bv2 = w.z; bc2 = c; }
        if (w.w > bv3) { bv3 = w.w; bc3 = c; }
    }

    const int4 t = reinterpret_cast<const int4*>(tgt)[i];

    unsigned int cTP[9], cT[9], cP[9];
#pragma unroll
    for (int j = 0; j < 9; ++j) { cTP[j] = 0u; cT[j] = 0u; cP[j] = 0u; }

    // per-component valid masks (t != 0), wave-uniform u64s
    const unsigned long long vx = __ballot(t.x != 0);
    const unsigned long long vy = __ballot(t.y != 0);
    const unsigned long long vz = __ballot(t.z != 0);
    const unsigned long long vw = __ballot(t.w != 0);

#pragma unroll
    for (int c = 1; c <= 9; ++c) {
        const int j = c - 1;
        {   // component x
            const unsigned long long tm = __ballot(t.x == c);
            const unsigned long long pm = __ballot(bc0 == c);
            cT[j]  += (unsigned int)__builtin_popcountll(tm);
            cP[j]  += (unsigned int)__builtin_popcountll(pm & vx);
            cTP[j] += (unsigned int)__builtin_popcountll(tm & pm);
        }
        {   // component y
            const unsigned long long tm = __ballot(t.y == c);
            const unsigned long long pm = __ballot(bc1 == c);
            cT[j]  += (unsigned int)__builtin_popcountll(tm);
            cP[j]  += (unsigned int)__builtin_popcountll(pm & vy);
            cTP[j] += (unsigned int)__builtin_popcountll(tm & pm);
        }
        {   // component z
            const unsigned long long tm = __ballot(t.z == c);
            const unsigned long long pm = __ballot(bc2 == c);
            cT[j]  += (unsigned int)__builtin_popcountll(tm);
            cP[j]  += (unsigned int)__builtin_popcountll(pm & vz);
            cTP[j] += (unsigned int)__builtin_popcountll(tm & pm);
        }
        {   // component w
            const unsigned long long tm = __ballot(t.w == c);
            const unsigned long long pm = __ballot(bc3 == c);
            cT[j]  += (unsigned int)__builtin_popcountll(tm);
            cP[j]  += (unsigned int)__builtin_popcountll(pm & vw);
            cTP[j] += (unsigned int)__builtin_popcountll(tm & pm);
        }
    }

    // combine 16 waves via plain LDS stores (counts are wave-uniform)
    if (lane == 0) {
#pragma unroll
        for (int j = 0; j < 9; ++j) {
            s[wave][j]      = cTP[j];
            s[wave][9 + j]  = cT[j];
            s[wave][18 + j] = cP[j];
        }
    }
    __syncthreads();

    // block total -> replica accumulator (27 atomics, one 128B line per replica)
    if (tid < 27) {
        unsigned int sum = 0;
#pragma unroll
        for (int wv = 0; wv < 16; ++wv) sum += s[wv][tid];
        atomicAdd(&ws[(blockIdx.x & (NREP - 1)) * 32 + tid], sum);
    }
    // __syncthreads drains vmcnt(0): accumulation atomics complete (coherent
    // point) before the done-counter atomic below can be issued.
    __syncthreads();
    __shared__ unsigned int lastFlag;
    if (tid == 0)
        lastFlag = (atomicAdd(&ws[NREP * 32], 1u) == NBLK - 1) ? 1u : 0u;
    __syncthreads();
    if (!lastFlag) return;

    // ---- last block: coherent readback of 64x27 replicas + epilogue ----
    __shared__ unsigned int cnt[27];
    if (tid < 27) cnt[tid] = 0u;
    __syncthreads();
    if (tid < NREP * 32) {
        const int c = tid & 31;
        if (c < 27) {
            const unsigned int v2 = atomicAdd(&ws[tid], 0u);  // coherent load
            if (v2) atomicAdd(&cnt[c], v2);                   // LDS, low contention
        }
    }
    __syncthreads();
    if (tid == 0) {
        double loss = 0.0;
#pragma unroll
        for (int c = 0; c < 9; ++c) {
            const double TP = (double)cnt[c];
            const double FN = (double)cnt[9 + c]  - TP;
            const double FP = (double)cnt[18 + c] - TP;
            const double tv = (TP + 1.0) / (TP + 0.7 * FN + 0.3 * FP + 1.0);
            loss += pow(1.0 - tv, 4.0 / 3.0);
        }
        out[0] = (float)loss;
    }
}

extern "C" void kernel_launch(void* const* d_in, const int* in_sizes, int n_in,
                              void* d_out, int out_size, void* d_ws, size_t ws_size,
                              hipStream_t stream) {
    const float* inp = (const float*)d_in[0];
    const int*   tgt = (const int*)d_in[1];
    unsigned int* ws = (unsigned int*)d_ws;   // 64*32 replicas + done counter
    float* out = (float*)d_out;

    hipMemsetAsync(ws, 0, (NREP * 32 + 1) * sizeof(unsigned int), stream);
    ftl_fused<<<dim3(NBLK), dim3(BLKT), 0, stream>>>(inp, tgt, ws, out);
}

// Round 3
// 131.738 us; speedup vs baseline: 3.1242x; 1.0339x over previous
//
#include <hip/hip_runtime.h>

// Focal Tversky loss over (8,10,512,512) fp32 logits, (8,512,512) int32 targets.
// argmax(softmax(x)) == argmax(x) -> no softmax needed. Memory-bound:
// channels 1..9 (75.5 MB) + targets (8.4 MB) ~= 84 MB read once -> ~13 us floor.
//
// R2: ballot-based wave histogramming, two kernels, no atomics.   [132.0 us]
// R3: fused, 28 same-line device atomics/block                    [411.6 us FAIL:
//     single-line coherent-point serialization, 57K ops ~ 325 us kernel]
// R4: fused, 64 replica lines + done-counter + memset             [136.2 us:
//     kernel fast (<51 us) but memset node + last-block tail epilogue cost
//     ~4 us MORE than the tiny reduce launch it replaced. Fusion falsified.]
// R5 (this round): restore the verified R2 structure — two kernels, plain-store
//     partials (no workspace init needed), no device atomics anywhere. Timed
//     region is dominated by 2x ~51 us harness re-poison fills (320 MiB each,
//     82% HBM peak); controllable slice is ~29 us of which ~13 us is the
//     mandatory 84 MB read. This is the best-measured configuration.

#define HW4     65536    // 512*512/4 (float4 groups per plane), = 2^16
#define NGROUPS 524288   // 8 * HW4
#define NBLK    2048     // hist grid; NBLK*256 == NGROUPS (one group per thread)

// partial layout (transposed for coalesced reduce): pw[c*NBLK + block]
// c in [0,27): 0..8 TP, 9..17 target count, 18..26 pred count
__global__ __launch_bounds__(256) void ftl_hist(const float* __restrict__ inp,
                                                const int* __restrict__ tgt,
                                                unsigned int* __restrict__ pw) {
    __shared__ unsigned int s[4][27];
    const int tid  = threadIdx.x;
    const int wave = tid >> 6;
    const int lane = tid & 63;

    const int i  = blockIdx.x * 256 + tid;     // 4-pixel group index
    const int b  = i >> 16;                    // image index
    const int gi = i & (HW4 - 1);              // group within image

    const float4* base = reinterpret_cast<const float4*>(inp)
                       + (((size_t)(b * 10 + 1)) << 16) + gi;  // channel 1

    float4 v = base[0];
    float bv0 = v.x, bv1 = v.y, bv2 = v.z, bv3 = v.w;
    int   bc0 = 1,   bc1 = 1,   bc2 = 1,   bc3 = 1;
#pragma unroll
    for (int c = 2; c <= 9; ++c) {
        float4 w = base[((size_t)(c - 1)) << 16];
        if (w.x > bv0) { bv0 = w.x; bc0 = c; }
        if (w.y > bv1) { bv1 = w.y; bc1 = c; }
        if (w.z > bv2) { bv2 = w.z; bc2 = c; }
        if (w.w > bv3) { bv3 = w.w; bc3 = c; }
    }

    const int4 t = reinterpret_cast<const int4*>(tgt)[i];

    unsigned int cTP[9], cT[9], cP[9];
#pragma unroll
    for (int j = 0; j < 9; ++j) { cTP[j] = 0u; cT[j] = 0u; cP[j] = 0u; }

    // per-component valid masks (t != 0), wave-uniform u64s
    const unsigned long long vx = __ballot(t.x != 0);
    const unsigned long long vy = __ballot(t.y != 0);
    const unsigned long long vz = __ballot(t.z != 0);
    const unsigned long long vw = __ballot(t.w != 0);

#pragma unroll
    for (int c = 1; c <= 9; ++c) {
        const int j = c - 1;
        {   // component x
            const unsigned long long tm = __ballot(t.x == c);
            const unsigned long long pm = __ballot(bc0 == c);
            cT[j]  += (unsigned int)__builtin_popcountll(tm);
            cP[j]  += (unsigned int)__builtin_popcountll(pm & vx);
            cTP[j] += (unsigned int)__builtin_popcountll(tm & pm);
        }
        {   // component y
            const unsigned long long tm = __ballot(t.y == c);
            const unsigned long long pm = __ballot(bc1 == c);
            cT[j]  += (unsigned int)__builtin_popcountll(tm);
            cP[j]  += (unsigned int)__builtin_popcountll(pm & vy);
            cTP[j] += (unsigned int)__builtin_popcountll(tm & pm);
        }
        {   // component z
            const unsigned long long tm = __ballot(t.z == c);
            const unsigned long long pm = __ballot(bc2 == c);
            cT[j]  += (unsigned int)__builtin_popcountll(tm);
            cP[j]  += (unsigned int)__builtin_popcountll(pm & vz);
            cTP[j] += (unsigned int)__builtin_popcountll(tm & pm);
        }
        {   // component w
            const unsigned long long tm = __ballot(t.w == c);
            const unsigned long long pm = __ballot(bc3 == c);
            cT[j]  += (unsigned int)__builtin_popcountll(tm);
            cP[j]  += (unsigned int)__builtin_popcountll(pm & vw);
            cTP[j] += (unsigned int)__builtin_popcountll(tm & pm);
        }
    }

    // combine 4 waves via plain LDS stores (counts are wave-uniform)
    if (lane == 0) {
#pragma unroll
        for (int j = 0; j < 9; ++j) {
            s[wave][j]      = cTP[j];
            s[wave][9 + j]  = cT[j];
            s[wave][18 + j] = cP[j];
        }
    }
    __syncthreads();
    if (tid < 27)
        pw[tid * NBLK + blockIdx.x] = s[0][tid] + s[1][tid] + s[2][tid] + s[3][tid];
}

// One block, 864 = 27*32 threads: each 32-lane group sums one counter row
// (coalesced), shuffle-reduce, thread 0 does the 9-term Tversky sum in double.
__global__ __launch_bounds__(864) void ftl_reduce(const unsigned int* __restrict__ pw,
                                                  float* __restrict__ out) {
    __shared__ double cs[27];
    const int tid = threadIdx.x;
    const int g = tid >> 5;
    const int l = tid & 31;
    {
        unsigned int sum = 0;
        const unsigned int* row = pw + g * NBLK;
#pragma unroll 8
        for (int k = l; k < NBLK; k += 32) sum += row[k];
#pragma unroll
        for (int off = 16; off; off >>= 1) sum += __shfl_down(sum, off, 32);
        if (l == 0) cs[g] = (double)sum;
    }
    __syncthreads();
    if (tid == 0) {
        double loss = 0.0;
#pragma unroll
        for (int c = 0; c < 9; ++c) {
            const double TP = cs[c];
            const double FN = cs[9 + c]  - TP;
            const double FP = cs[18 + c] - TP;
            const double tv = (TP + 1.0) / (TP + 0.7 * FN + 0.3 * FP + 1.0);
            loss += pow(1.0 - tv, 4.0 / 3.0);
        }
        out[0] = (float)loss;
    }
}

extern "C" void kernel_launch(void* const* d_in, const int* in_sizes, int n_in,
                              void* d_out, int out_size, void* d_ws, size_t ws_size,
                              hipStream_t stream) {
    const float* inp = (const float*)d_in[0];
    const int*   tgt = (const int*)d_in[1];
    unsigned int* pw = (unsigned int*)d_ws;    // 27*2048 partial counters, no init needed
    float* out = (float*)d_out;

    ftl_hist<<<dim3(NBLK), dim3(256), 0, stream>>>(inp, tgt, pw);
    ftl_reduce<<<dim3(1), dim3(864), 0, stream>>>(pw, out);
}